// Round 1
// baseline (141.882 us; speedup 1.0000x reference)
//
#include <hip/hip_runtime.h>

// out[i, :] = weight[b[i], :]  (float32, Y_DIM=32), with out[0, :] = 0.
// One thread per float4 of output → 8 threads per cell, fully coalesced.

__global__ __launch_bounds__(256) void batch_effect_gather_kernel(
        const int* __restrict__ b,
        const float4* __restrict__ w4,   // weight viewed as [N_BATCHES, 8] float4
        float4* __restrict__ out4,       // output viewed as [N, 8] float4
        int n_vec) {                     // N * 8
    int g = blockIdx.x * 256 + threadIdx.x;
    if (g >= n_vec) return;
    int cell = g >> 3;       // which of the N cells
    int j    = g & 7;        // which float4 within the row
    int batch = b[cell];     // broadcast across the 8 lanes of this cell
    float4 v = w4[batch * 8 + j];
    if (cell == 0) v = make_float4(0.f, 0.f, 0.f, 0.f);
    out4[g] = v;
}

extern "C" void kernel_launch(void* const* d_in, const int* in_sizes, int n_in,
                              void* d_out, int out_size, void* d_ws, size_t ws_size,
                              hipStream_t stream) {
    const int*    b  = (const int*)d_in[0];     // [N, 1] int32
    const float4* w4 = (const float4*)d_in[1];  // [64, 32] f32 → [64, 8] float4
    float4* out4 = (float4*)d_out;              // [N, 32] f32 → [N, 8] float4

    int n = in_sizes[0];          // N (b has N elements)
    int n_vec = n * 8;            // total float4 chunks of output
    int blocks = (n_vec + 255) / 256;
    batch_effect_gather_kernel<<<blocks, 256, 0, stream>>>(b, w4, out4, n_vec);
}